// Round 3
// baseline (763.292 us; speedup 1.0000x reference)
//
#include <hip/hip_runtime.h>

#define D_MODEL 512
#define D_FF    2048
#define NEXP    8
#define TOKENS  8192
#define TROWS   25600     // 8192 universal + 16384 expert slots + padding

typedef __bf16 bf16_t;
typedef __attribute__((ext_vector_type(8))) __bf16 bf16x8_t;
typedef __attribute__((ext_vector_type(4))) __bf16 bf16x4_t;
typedef __attribute__((ext_vector_type(4))) float  f32x4_t;

// ---- workspace layout (bytes) ----
#define W1P_OFF    0u            // bf16 [8][16][2048][32]   k-slab pack of w1
#define UW1P_OFF   16777216u     // bf16 [16][2048][32]
#define W2P_OFF    18874368u     // bf16 [8][64][512][32]
#define UW2P_OFF   35651584u     // bf16 [64][512][32]
#define S0_OFF     37748736u     // bf16 [8192][512]
#define S1_OFF     46137344u     // bf16 [8192][512]
#define CNT_OFF    54525952u     // int[16]
#define TOKL_OFF   54526016u     // int  [8][8192]  entry=(token<<1)|slot
#define GATEL_OFF  54788160u     // float[8][8192]
#define OMEGA_OFF  55050304u     // float[8192]
#define TLOG_OFF   55083072u     // double[8][8]
#define SOFF_OFF   55083584u     // int[16] section row offsets
#define SPC_OFF    55083648u     // int[16] section padded counts
#define RMETA_OFF  55083712u     // int[25600]  (tok<<2)|slot; slot 0/1 expert,2 univ,3 pad
#define RGATE_OFF  55186112u     // float[25600]
#define XGP_OFF    55288512u     // bf16 [16][25600][32]  k-slab gathered X
#define HP_OFF     81502912u     // bf16 [64][25600][32]  k-slab h

__device__ inline f32x4_t mfma_bf16(bf16x8_t a, bf16x8_t b, f32x4_t c) {
  return __builtin_amdgcn_mfma_f32_16x16x32_bf16(a, b, c, 0, 0, 0);
}

__device__ __forceinline__ void load_lds16(const void* g, void* l) {
  __builtin_amdgcn_global_load_lds(
      (const __attribute__((address_space(1))) unsigned int*)g,
      (__attribute__((address_space(3))) unsigned int*)l, 16, 0, 0);
}

// pack in[R][C] f32 -> out[R/32][C][32] bf16   (out[s][c][j] = in[s*32+j][c])
__global__ void k_pack(const float* __restrict__ in, bf16_t* __restrict__ out, int R, int C) {
  __shared__ float tile[64][65];
  const size_t mat = (size_t)blockIdx.z * R * C;
  in  += mat;
  out += mat;
  int r0 = blockIdx.y * 64, c0 = blockIdx.x * 64;
  for (int i = threadIdx.x; i < 4096; i += 256) {
    int r = i >> 6, c = i & 63;
    tile[r][c] = in[(size_t)(r0 + r) * C + c0 + c];
  }
  __syncthreads();
  int item = threadIdx.x >> 1, jh = threadIdx.x & 1;
  int c = item & 63, s = item >> 6;
  union { bf16_t h[16]; uint4 u[2]; } t;
#pragma unroll
  for (int k = 0; k < 16; k++) t.h[k] = (bf16_t)tile[s * 32 + jh * 16 + k][c];
  char* dst = (char*)out + ((size_t)((r0 >> 5) + s) * C + (c0 + c)) * 64 + jh * 32;
  ((uint4*)dst)[0] = t.u[0];
  ((uint4*)dst)[1] = t.u[1];
}

__global__ void k_tlog(const int* __restrict__ task_ids, const float* __restrict__ task_emb,
                       const float* __restrict__ gate_w, const float* __restrict__ gate_b,
                       double* __restrict__ tlog) {
  int i = threadIdx.x;
  if (i >= 64) return;
  int b = i >> 3, e = i & 7;
  const float* te = task_emb + (size_t)task_ids[b] * D_MODEL;
  double acc = (double)gate_b[e];
  for (int d = 0; d < D_MODEL; d++)
    acc += (double)te[d] * (double)gate_w[(size_t)(D_MODEL + d) * NEXP + e];
  tlog[i] = acc;
}

__global__ void k_gate(const float* __restrict__ x, const float* __restrict__ gate_w,
                       const double* __restrict__ tlog,
                       float* __restrict__ logits_out,
                       int* __restrict__ counts, int* __restrict__ tokl,
                       float* __restrict__ gatel, float* __restrict__ omega) {
  int gtid = blockIdx.x * blockDim.x + threadIdx.x;
  int t = gtid >> 6;
  int lane = gtid & 63;
  if (t >= TOKENS) return;
  const float* xr = x + (size_t)t * D_MODEL;
  int d0 = lane * 8;
  float4 xa = *(const float4*)(xr + d0);
  float4 xc = *(const float4*)(xr + d0 + 4);
  float xv[8] = {xa.x, xa.y, xa.z, xa.w, xc.x, xc.y, xc.z, xc.w};
  double acc[NEXP];
#pragma unroll
  for (int e = 0; e < NEXP; e++) acc[e] = 0.0;
#pragma unroll
  for (int j = 0; j < 8; j++) {
    const float* gwr = gate_w + (size_t)(d0 + j) * NEXP;
    float4 g0 = *(const float4*)gwr;
    float4 g1 = *(const float4*)(gwr + 4);
    double xd = (double)xv[j];
    acc[0] += xd * (double)g0.x; acc[1] += xd * (double)g0.y;
    acc[2] += xd * (double)g0.z; acc[3] += xd * (double)g0.w;
    acc[4] += xd * (double)g1.x; acc[5] += xd * (double)g1.y;
    acc[6] += xd * (double)g1.z; acc[7] += xd * (double)g1.w;
  }
#pragma unroll
  for (int off = 32; off > 0; off >>= 1) {
#pragma unroll
    for (int e = 0; e < NEXP; e++) acc[e] += __shfl_xor(acc[e], off);
  }
  if (lane == 0) {
    int b = t >> 10;
    double lg[NEXP];
#pragma unroll
    for (int e = 0; e < NEXP; e++) {
      lg[e] = acc[e] + tlog[b * NEXP + e];
      logits_out[(size_t)t * NEXP + e] = (float)lg[e];
    }
    int e0 = 0;
    for (int e = 1; e < NEXP; e++) if (lg[e] > lg[e0]) e0 = e;
    int e1 = (e0 == 0) ? 1 : 0;
    for (int e = 0; e < NEXP; e++) if (e != e0 && lg[e] > lg[e1]) e1 = e;
    double p0 = 1.0 / (1.0 + exp(lg[e1] - lg[e0]));
    float g0f = (float)p0;
    float g1f = (float)(1.0 - p0);
    omega[t] = 1.0f - g0f;
    int i0 = atomicAdd(counts + e0, 1);
    tokl[e0 * TOKENS + i0]  = (t << 1);
    gatel[e0 * TOKENS + i0] = g0f;
    int i1 = atomicAdd(counts + e1, 1);
    tokl[e1 * TOKENS + i1]  = (t << 1) | 1;
    gatel[e1 * TOKENS + i1] = g1f;
  }
}

// tiny: section offsets from counts
__global__ void k_soff(const int* __restrict__ cnts, int* __restrict__ soff, int* __restrict__ spc) {
  if (threadIdx.x == 0) {
    soff[8] = 0; spc[8] = TOKENS;
    int off = TOKENS;
    for (int e = 0; e < 8; e++) {
      int c = cnts[e];
      int p = (c + 127) & ~127;
      soff[e] = off; spc[e] = p;
      off += p;
    }
  }
}

// parallel row-metadata fill
__global__ void k_fill(const int* __restrict__ cnts, const int* __restrict__ soff,
                       const int* __restrict__ spc,
                       const int* __restrict__ tokl, const float* __restrict__ gatel,
                       const float* __restrict__ omega,
                       int* __restrict__ rmeta, float* __restrict__ rgate) {
  int r = blockIdx.x * 256 + threadIdx.x;
  if (r >= TROWS) return;
  if (r < TOKENS) { rmeta[r] = (r << 2) | 2; rgate[r] = omega[r]; return; }
  int meta = 3; float g = 0.f;
#pragma unroll
  for (int e = 0; e < 8; e++) {
    int off = soff[e];
    if (r >= off && r < off + spc[e]) {
      int i = r - off;
      if (i < cnts[e]) {
        int en = tokl[e * TOKENS + i];
        meta = ((en >> 1) << 2) | (en & 1);
        g = gatel[e * TOKENS + i];
      }
      break;
    }
  }
  rmeta[r] = meta; rgate[r] = g;
}

// gather X rows (f32 -> bf16) into k-slab layout xgp[s][row][32]
__global__ void k_gather(const float* __restrict__ x, const int* __restrict__ rmeta,
                         bf16_t* __restrict__ xgp) {
  int rbase = blockIdx.x * 128;
  for (int it = 0; it < 8; it++) {
    int id = it * 256 + threadIdx.x;
    int row = rbase + (id >> 4), s = id & 15;
    int meta = rmeta[row];
    union { bf16_t h[32]; uint4 u[4]; } t;
    if ((meta & 3) == 3) {
#pragma unroll
      for (int j = 0; j < 4; j++) t.u[j] = uint4{0, 0, 0, 0};
    } else {
      const float* src = x + (size_t)(meta >> 2) * D_MODEL + s * 32;
#pragma unroll
      for (int j = 0; j < 32; j += 4) {
        float4 v = *(const float4*)(src + j);
        t.h[j] = (bf16_t)v.x; t.h[j + 1] = (bf16_t)v.y;
        t.h[j + 2] = (bf16_t)v.z; t.h[j + 3] = (bf16_t)v.w;
      }
    }
    char* dst = (char*)xgp + ((size_t)s * TROWS + row) * 64;
#pragma unroll
    for (int j = 0; j < 4; j++) ((uint4*)dst)[j] = t.u[j];
  }
}

// GEMM1: h[rows][2048] = gelu(Xg @ W1 + b1); BK=64, hoisted staging pointers
__global__ __launch_bounds__(256) void k_gemm1(
    const bf16_t* __restrict__ xgp, const bf16_t* __restrict__ w1p,
    const bf16_t* __restrict__ uw1p,
    const float* __restrict__ b1, const float* __restrict__ ub1,
    const int* __restrict__ soff, const int* __restrict__ spc,
    bf16_t* __restrict__ hp) {
  const int sec = blockIdx.z, mt = blockIdx.x, ft = blockIdx.y;
  if (mt * 128 >= spc[sec]) return;
  const int groff = soff[sec];
  const char* Bbase = (const char*)((sec == 8) ? uw1p : (w1p + (size_t)sec * 16 * D_FF * 32));
  const float* bias = (sec == 8) ? ub1 : (b1 + sec * D_FF);

  __shared__ char smem[34816];   // tiles: A 16KB @0, B 16KB @16384; epilogue overlay 128*136*2
  const int tid = threadIdx.x, wave = tid >> 6, lane = tid & 63;
  const int l16 = lane & 15, quad = lane >> 4;
  const int wm = wave & 1, wn = wave >> 1;

  f32x4_t acc[4][4];
#pragma unroll
  for (int i = 0; i < 4; i++)
#pragma unroll
    for (int j = 0; j < 4; j++) acc[i][j] = f32x4_t{0.f, 0.f, 0.f, 0.f};

  // per-wave staging: waves 0,1 -> A slabs 0,1; waves 2,3 -> B slabs 0,1.
  // each wave stages a contiguous 8KB run (16 rows per 1KB instr).
  const int slab = wave & 1;
  const char* gp;
  size_t gstride;
  if (wave < 2) {
    gp = (const char*)xgp + ((size_t)slab * TROWS + groff + mt * 128) * 64 + lane * 16;
    gstride = (size_t)2 * TROWS * 64;
  } else {
    gp = Bbase + ((size_t)slab * D_FF + ft * 128) * 64 + lane * 16;
    gstride = (size_t)2 * D_FF * 64;
  }
  char* lp = smem + (wave < 2 ? 0 : 16384) + slab * 8192;

  for (int st = 0; st < 8; st++) {
#pragma unroll
    for (int i = 0; i < 8; i++)
      load_lds16(gp + i * 1024, lp + i * 1024);
    gp += gstride;
    __syncthreads();
#pragma unroll
    for (int ks = 0; ks < 2; ks++) {
      bf16x8_t af[4], bfr[4];
#pragma unroll
      for (int f = 0; f < 4; f++)
        af[f] = *(const bf16x8_t*)(smem + ks * 8192 + (wm * 64 + f * 16 + l16) * 64 + quad * 16);
#pragma unroll
      for (int f = 0; f < 4; f++)
        bfr[f] = *(const bf16x8_t*)(smem + 16384 + ks * 8192 + (wn * 64 + f * 16 + l16) * 64 + quad * 16);
#pragma unroll
      for (int fm = 0; fm < 4; fm++)
#pragma unroll
        for (int fn = 0; fn < 4; fn++)
          acc[fm][fn] = mfma_bf16(af[fm], bfr[fn], acc[fm][fn]);
    }
    __syncthreads();
  }

  // epilogue: bias + exact gelu -> LDS [128][136] bf16 -> hp k-slab
  bf16_t* ep = (bf16_t*)smem;
#pragma unroll
  for (int fm = 0; fm < 4; fm++)
#pragma unroll
    for (int fn = 0; fn < 4; fn++)
#pragma unroll
      for (int i = 0; i < 4; i++) {
        int row = wm * 64 + fm * 16 + quad * 4 + i;
        int col = wn * 64 + fn * 16 + l16;
        float v = acc[fm][fn][i] + bias[ft * 128 + col];
        float gv = 0.5f * v * (1.0f + erff(v * 0.70710678118654752f));
        ep[row * 136 + col] = (bf16_t)gv;
      }
  __syncthreads();
#pragma unroll
  for (int i = 0; i < 2; i++) {
    int id = i * 256 + tid;
    int row = id & 127, cc = id >> 7;
    const uint4* src = (const uint4*)(ep + row * 136 + cc * 32);
    char* dst = (char*)hp + ((size_t)(ft * 4 + cc) * TROWS + groff + mt * 128 + row) * 64;
#pragma unroll
    for (int j = 0; j < 4; j++) ((uint4*)dst)[j] = src[j];
  }
}

// GEMM2: y[rows][512] = h @ W2 + b2, gate-scale, scatter; BK=64
__global__ __launch_bounds__(256) void k_gemm2(
    const bf16_t* __restrict__ hp, const bf16_t* __restrict__ w2p,
    const bf16_t* __restrict__ uw2p,
    const float* __restrict__ b2, const float* __restrict__ ub2,
    const int* __restrict__ soff, const int* __restrict__ spc,
    const int* __restrict__ rmeta, const float* __restrict__ rgate,
    bf16_t* __restrict__ s0, bf16_t* __restrict__ s1, float* __restrict__ out) {
  const int sec = blockIdx.z, mt = blockIdx.x, nt = blockIdx.y;
  if (mt * 128 >= spc[sec]) return;
  const int groff = soff[sec];
  const char* Bbase = (const char*)((sec == 8) ? uw2p : (w2p + (size_t)sec * 64 * D_MODEL * 32));
  const float* bias = (sec == 8) ? ub2 : (b2 + sec * D_MODEL);

  __shared__ char smem[32768];
  const int tid = threadIdx.x, wave = tid >> 6, lane = tid & 63;
  const int l16 = lane & 15, quad = lane >> 4;
  const int wm = wave & 1, wn = wave >> 1;

  f32x4_t acc[4][4];
#pragma unroll
  for (int i = 0; i < 4; i++)
#pragma unroll
    for (int j = 0; j < 4; j++) acc[i][j] = f32x4_t{0.f, 0.f, 0.f, 0.f};

  const int slab = wave & 1;
  const char* gp;
  size_t gstride;
  if (wave < 2) {
    gp = (const char*)hp + ((size_t)slab * TROWS + groff + mt * 128) * 64 + lane * 16;
    gstride = (size_t)2 * TROWS * 64;
  } else {
    gp = Bbase + ((size_t)slab * D_MODEL + nt * 128) * 64 + lane * 16;
    gstride = (size_t)2 * D_MODEL * 64;
  }
  char* lp = smem + (wave < 2 ? 0 : 16384) + slab * 8192;

  for (int st = 0; st < 32; st++) {
#pragma unroll
    for (int i = 0; i < 8; i++)
      load_lds16(gp + i * 1024, lp + i * 1024);
    gp += gstride;
    __syncthreads();
#pragma unroll
    for (int ks = 0; ks < 2; ks++) {
      bf16x8_t af[4], bfr[4];
#pragma unroll
      for (int f = 0; f < 4; f++)
        af[f] = *(const bf16x8_t*)(smem + ks * 8192 + (wm * 64 + f * 16 + l16) * 64 + quad * 16);
#pragma unroll
      for (int f = 0; f < 4; f++)
        bfr[f] = *(const bf16x8_t*)(smem + 16384 + ks * 8192 + (wn * 64 + f * 16 + l16) * 64 + quad * 16);
#pragma unroll
      for (int fm = 0; fm < 4; fm++)
#pragma unroll
        for (int fn = 0; fn < 4; fn++)
          acc[fm][fn] = mfma_bf16(af[fm], bfr[fn], acc[fm][fn]);
    }
    __syncthreads();
  }

  // epilogue: +b2, *gate, scatter by slot
#pragma unroll
  for (int fm = 0; fm < 4; fm++) {
#pragma unroll
    for (int i = 0; i < 4; i++) {
      int grow = groff + mt * 128 + wm * 64 + fm * 16 + quad * 4 + i;
      int meta = rmeta[grow];
      int slot = meta & 3;
      if (slot == 3) continue;
      float g = rgate[grow];
      size_t tkoff = (size_t)(meta >> 2) * D_MODEL;
      if (slot == 2) {
        float* dst = out + tkoff;
#pragma unroll
        for (int fn = 0; fn < 4; fn++) {
          int d = nt * 128 + wn * 64 + fn * 16 + l16;
          dst[d] = (acc[fm][fn][i] + bias[d]) * g;
        }
      } else {
        bf16_t* dst = (slot ? s1 : s0) + tkoff;
#pragma unroll
        for (int fn = 0; fn < 4; fn++) {
          int d = nt * 128 + wn * 64 + fn * 16 + l16;
          dst[d] = (bf16_t)((acc[fm][fn][i] + bias[d]) * g);
        }
      }
    }
  }
}

__global__ void k_combine(const bf16x4_t* __restrict__ s0, const bf16x4_t* __restrict__ s1,
                          float4* __restrict__ out, int n4) {
  int i = blockIdx.x * blockDim.x + threadIdx.x;
  if (i >= n4) return;
  bf16x4_t a = s0[i], b = s1[i];
  float4 o = out[i];
  o.x += (float)a[0] + (float)b[0];
  o.y += (float)a[1] + (float)b[1];
  o.z += (float)a[2] + (float)b[2];
  o.w += (float)a[3] + (float)b[3];
  out[i] = o;
}

extern "C" void kernel_launch(void* const* d_in, const int* in_sizes, int n_in,
                              void* d_out, int out_size, void* d_ws, size_t ws_size,
                              hipStream_t stream) {
  (void)in_sizes; (void)n_in; (void)out_size; (void)ws_size;
  const float* x        = (const float*)d_in[0];
  const int*   task_ids = (const int*)  d_in[1];
  const float* task_emb = (const float*)d_in[2];
  const float* gate_w   = (const float*)d_in[3];
  const float* gate_b   = (const float*)d_in[4];
  const float* w1       = (const float*)d_in[5];
  const float* b1       = (const float*)d_in[6];
  const float* w2       = (const float*)d_in[7];
  const float* b2       = (const float*)d_in[8];
  const float* uw1      = (const float*)d_in[9];
  const float* ub1      = (const float*)d_in[10];
  const float* uw2      = (const float*)d_in[11];
  const float* ub2      = (const float*)d_in[12];

  char* ws = (char*)d_ws;
  bf16_t* w1p   = (bf16_t*)(ws + W1P_OFF);
  bf16_t* uw1p  = (bf16_t*)(ws + UW1P_OFF);
  bf16_t* w2p   = (bf16_t*)(ws + W2P_OFF);
  bf16_t* uw2p  = (bf16_t*)(ws + UW2P_OFF);
  bf16_t* s0    = (bf16_t*)(ws + S0_OFF);
  bf16_t* s1    = (bf16_t*)(ws + S1_OFF);
  int*    cnts  = (int*)   (ws + CNT_OFF);
  int*    tokl  = (int*)   (ws + TOKL_OFF);
  float*  gatel = (float*) (ws + GATEL_OFF);
  float*  omg   = (float*) (ws + OMEGA_OFF);
  double* tlog  = (double*)(ws + TLOG_OFF);
  int*    soff  = (int*)   (ws + SOFF_OFF);
  int*    spc   = (int*)   (ws + SPC_OFF);
  int*    rmeta = (int*)   (ws + RMETA_OFF);
  float*  rgate = (float*) (ws + RGATE_OFF);
  bf16_t* xgp   = (bf16_t*)(ws + XGP_OFF);
  bf16_t* hp    = (bf16_t*)(ws + HP_OFF);

  float* out    = (float*)d_out;
  float* logits = out + (size_t)TOKENS * D_MODEL;

  hipMemsetAsync(cnts, 0, 64, stream);

  k_pack<<<dim3(32, 8, NEXP), 256, 0, stream>>>(w1, w1p, D_MODEL, D_FF);
  k_pack<<<dim3(8, 32, NEXP), 256, 0, stream>>>(w2, w2p, D_FF, D_MODEL);
  k_pack<<<dim3(32, 8, 1),    256, 0, stream>>>(uw1, uw1p, D_MODEL, D_FF);
  k_pack<<<dim3(8, 32, 1),    256, 0, stream>>>(uw2, uw2p, D_FF, D_MODEL);
  k_tlog<<<1, 64, 0, stream>>>(task_ids, task_emb, gate_w, gate_b, tlog);
  k_gate<<<dim3(TOKENS / 4), 256, 0, stream>>>(x, gate_w, tlog, logits, cnts, tokl, gatel, omg);
  k_soff<<<1, 64, 0, stream>>>(cnts, soff, spc);
  k_fill<<<dim3((TROWS + 255) / 256), 256, 0, stream>>>(cnts, soff, spc, tokl, gatel, omg,
                                                        rmeta, rgate);
  k_gather<<<dim3(TROWS / 128), 256, 0, stream>>>(x, rmeta, xgp);
  k_gemm1<<<dim3(64, 16, 9), 256, 0, stream>>>(xgp, w1p, uw1p, b1, ub1, soff, spc, hp);
  k_gemm2<<<dim3(64, 4, 9), 256, 0, stream>>>(hp, w2p, uw2p, b2, ub2, soff, spc,
                                              rmeta, rgate, s0, s1, out);
  const int n4 = TOKENS * D_MODEL / 4;
  k_combine<<<dim3(n4 / 256), 256, 0, stream>>>((const bf16x4_t*)s0, (const bf16x4_t*)s1,
                                                (float4*)out, n4);
}

// Round 5
// 665.597 us; speedup vs baseline: 1.1468x; 1.1468x over previous
//
#include <hip/hip_runtime.h>

#define D_MODEL 512
#define D_FF    2048
#define NEXP    8
#define TOKENS  8192
#define TROWS   25600     // 8192 universal + 16384 expert slots + padding

typedef __bf16 bf16_t;
typedef __attribute__((ext_vector_type(8))) __bf16 bf16x8_t;
typedef __attribute__((ext_vector_type(4))) __bf16 bf16x4_t;
typedef __attribute__((ext_vector_type(4))) float  f32x4_t;

// ---- workspace layout (bytes) ----
#define W1P_OFF    0u            // bf16 [8][16][2048][32]   k-slab pack of w1
#define UW1P_OFF   16777216u     // bf16 [16][2048][32]
#define W2P_OFF    18874368u     // bf16 [8][64][512][32]
#define UW2P_OFF   35651584u     // bf16 [64][512][32]
#define S0_OFF     37748736u     // bf16 [8192][512]
#define S1_OFF     46137344u     // bf16 [8192][512]
#define CNT_OFF    54525952u     // int[16]
#define TOKL_OFF   54526016u     // int  [8][8192]  entry=(token<<1)|slot
#define GATEL_OFF  54788160u     // float[8][8192]
#define OMEGA_OFF  55050304u     // float[8192]
#define TLOG_OFF   55083072u     // double[8][8]
#define SOFF_OFF   55083584u     // int[16] section row offsets
#define SPC_OFF    55083648u     // int[16] section padded counts
#define RMETA_OFF  55083712u     // int[25600]  (tok<<2)|slot; slot 0/1 expert,2 univ,3 pad
#define RGATE_OFF  55186112u     // float[25600]
#define XGP_OFF    55288512u     // bf16 [16][25600][32]  k-slab gathered X
#define HP_OFF     81502912u     // bf16 [64][25600][32]  k-slab h

__device__ inline f32x4_t mfma_bf16(bf16x8_t a, bf16x8_t b, f32x4_t c) {
  return __builtin_amdgcn_mfma_f32_16x16x32_bf16(a, b, c, 0, 0, 0);
}

__device__ __forceinline__ void load_lds16(const void* g, void* l) {
  __builtin_amdgcn_global_load_lds(
      (const __attribute__((address_space(1))) unsigned int*)g,
      (__attribute__((address_space(3))) unsigned int*)l, 16, 0, 0);
}

#define WAITCNT4   asm volatile("s_waitcnt vmcnt(4)" ::: "memory")
#define WAITCNT0   asm volatile("s_waitcnt vmcnt(0)" ::: "memory")
#define WAIT_LGKM0 asm volatile("s_waitcnt lgkmcnt(0)" ::: "memory")
#define RAWBAR     asm volatile("s_barrier" ::: "memory")

// pack in[R][C] f32 -> out[R/32][C][32] bf16   (out[s][c][j] = in[s*32+j][c])
__global__ void k_pack(const float* __restrict__ in, bf16_t* __restrict__ out, int R, int C) {
  __shared__ float tile[64][65];
  const size_t mat = (size_t)blockIdx.z * R * C;
  in  += mat;
  out += mat;
  int r0 = blockIdx.y * 64, c0 = blockIdx.x * 64;
  for (int i = threadIdx.x; i < 4096; i += 256) {
    int r = i >> 6, c = i & 63;
    tile[r][c] = in[(size_t)(r0 + r) * C + c0 + c];
  }
  __syncthreads();
  int item = threadIdx.x >> 1, jh = threadIdx.x & 1;
  int c = item & 63, s = item >> 6;
  union { bf16_t h[16]; uint4 u[2]; } t;
#pragma unroll
  for (int k = 0; k < 16; k++) t.h[k] = (bf16_t)tile[s * 32 + jh * 16 + k][c];
  char* dst = (char*)out + ((size_t)((r0 >> 5) + s) * C + (c0 + c)) * 64 + jh * 32;
  ((uint4*)dst)[0] = t.u[0];
  ((uint4*)dst)[1] = t.u[1];
}

__global__ void k_tlog(const int* __restrict__ task_ids, const float* __restrict__ task_emb,
                       const float* __restrict__ gate_w, const float* __restrict__ gate_b,
                       double* __restrict__ tlog) {
  int i = threadIdx.x;
  if (i >= 64) return;
  int b = i >> 3, e = i & 7;
  const float* te = task_emb + (size_t)task_ids[b] * D_MODEL;
  double acc = (double)gate_b[e];
  for (int d = 0; d < D_MODEL; d++)
    acc += (double)te[d] * (double)gate_w[(size_t)(D_MODEL + d) * NEXP + e];
  tlog[i] = acc;
}

__global__ void k_gate(const float* __restrict__ x, const float* __restrict__ gate_w,
                       const double* __restrict__ tlog,
                       float* __restrict__ logits_out,
                       int* __restrict__ counts, int* __restrict__ tokl,
                       float* __restrict__ gatel, float* __restrict__ omega) {
  int gtid = blockIdx.x * blockDim.x + threadIdx.x;
  int t = gtid >> 6;
  int lane = gtid & 63;
  if (t >= TOKENS) return;
  const float* xr = x + (size_t)t * D_MODEL;
  int d0 = lane * 8;
  float4 xa = *(const float4*)(xr + d0);
  float4 xc = *(const float4*)(xr + d0 + 4);
  float xv[8] = {xa.x, xa.y, xa.z, xa.w, xc.x, xc.y, xc.z, xc.w};
  double acc[NEXP];
#pragma unroll
  for (int e = 0; e < NEXP; e++) acc[e] = 0.0;
#pragma unroll
  for (int j = 0; j < 8; j++) {
    const float* gwr = gate_w + (size_t)(d0 + j) * NEXP;
    float4 g0 = *(const float4*)gwr;
    float4 g1 = *(const float4*)(gwr + 4);
    double xd = (double)xv[j];
    acc[0] += xd * (double)g0.x; acc[1] += xd * (double)g0.y;
    acc[2] += xd * (double)g0.z; acc[3] += xd * (double)g0.w;
    acc[4] += xd * (double)g1.x; acc[5] += xd * (double)g1.y;
    acc[6] += xd * (double)g1.z; acc[7] += xd * (double)g1.w;
  }
#pragma unroll
  for (int off = 32; off > 0; off >>= 1) {
#pragma unroll
    for (int e = 0; e < NEXP; e++) acc[e] += __shfl_xor(acc[e], off);
  }
  if (lane == 0) {
    int b = t >> 10;
    double lg[NEXP];
#pragma unroll
    for (int e = 0; e < NEXP; e++) {
      lg[e] = acc[e] + tlog[b * NEXP + e];
      logits_out[(size_t)t * NEXP + e] = (float)lg[e];
    }
    int e0 = 0;
    for (int e = 1; e < NEXP; e++) if (lg[e] > lg[e0]) e0 = e;
    int e1 = (e0 == 0) ? 1 : 0;
    for (int e = 0; e < NEXP; e++) if (e != e0 && lg[e] > lg[e1]) e1 = e;
    double p0 = 1.0 / (1.0 + exp(lg[e1] - lg[e0]));
    float g0f = (float)p0;
    float g1f = (float)(1.0 - p0);
    omega[t] = 1.0f - g0f;
    int i0 = atomicAdd(counts + e0, 1);
    tokl[e0 * TOKENS + i0]  = (t << 1);
    gatel[e0 * TOKENS + i0] = g0f;
    int i1 = atomicAdd(counts + e1, 1);
    tokl[e1 * TOKENS + i1]  = (t << 1) | 1;
    gatel[e1 * TOKENS + i1] = g1f;
  }
}

// tiny: section offsets from counts
__global__ void k_soff(const int* __restrict__ cnts, int* __restrict__ soff, int* __restrict__ spc) {
  if (threadIdx.x == 0) {
    soff[8] = 0; spc[8] = TOKENS;
    int off = TOKENS;
    for (int e = 0; e < 8; e++) {
      int c = cnts[e];
      int p = (c + 127) & ~127;
      soff[e] = off; spc[e] = p;
      off += p;
    }
  }
}

// parallel row-metadata fill
__global__ void k_fill(const int* __restrict__ cnts, const int* __restrict__ soff,
                       const int* __restrict__ spc,
                       const int* __restrict__ tokl, const float* __restrict__ gatel,
                       const float* __restrict__ omega,
                       int* __restrict__ rmeta, float* __restrict__ rgate) {
  int r = blockIdx.x * 256 + threadIdx.x;
  if (r >= TROWS) return;
  if (r < TOKENS) { rmeta[r] = (r << 2) | 2; rgate[r] = omega[r]; return; }
  int meta = 3; float g = 0.f;
#pragma unroll
  for (int e = 0; e < 8; e++) {
    int off = soff[e];
    if (r >= off && r < off + spc[e]) {
      int i = r - off;
      if (i < cnts[e]) {
        int en = tokl[e * TOKENS + i];
        meta = ((en >> 1) << 2) | (en & 1);
        g = gatel[e * TOKENS + i];
      }
      break;
    }
  }
  rmeta[r] = meta; rgate[r] = g;
}

// gather X rows (f32 -> bf16) into k-slab layout xgp[s][row][32]
__global__ void k_gather(const float* __restrict__ x, const int* __restrict__ rmeta,
                         bf16_t* __restrict__ xgp) {
  int rbase = blockIdx.x * 128;
  for (int it = 0; it < 8; it++) {
    int id = it * 256 + threadIdx.x;
    int row = rbase + (id >> 4), s = id & 15;
    int meta = rmeta[row];
    union { bf16_t h[32]; uint4 u[4]; } t;
    if ((meta & 3) == 3) {
#pragma unroll
      for (int j = 0; j < 4; j++) t.u[j] = uint4{0, 0, 0, 0};
    } else {
      const float* src = x + (size_t)(meta >> 2) * D_MODEL + s * 32;
#pragma unroll
      for (int j = 0; j < 32; j += 4) {
        float4 v = *(const float4*)(src + j);
        t.h[j] = (bf16_t)v.x; t.h[j + 1] = (bf16_t)v.y;
        t.h[j + 2] = (bf16_t)v.z; t.h[j + 3] = (bf16_t)v.w;
      }
    }
    char* dst = (char*)xgp + ((size_t)s * TROWS + row) * 64;
#pragma unroll
    for (int j = 0; j < 4; j++) ((uint4*)dst)[j] = t.u[j];
  }
}

// GEMM1: h[rows][2048] = gelu(Xg @ W1 + b1); BK=32, double-buffered raw-barrier pipeline
__global__ __launch_bounds__(256) void k_gemm1(
    const bf16_t* __restrict__ xgp, const bf16_t* __restrict__ w1p,
    const bf16_t* __restrict__ uw1p,
    const float* __restrict__ b1, const float* __restrict__ ub1,
    const int* __restrict__ soff, const int* __restrict__ spc,
    bf16_t* __restrict__ hp) {
  const int sec = blockIdx.z, mt = blockIdx.x, ft = blockIdx.y;
  if (mt * 128 >= spc[sec]) return;
  const int groff = soff[sec];
  const char* Bbase = (const char*)((sec == 8) ? uw1p : (w1p + (size_t)sec * 16 * D_FF * 32));
  const float* bias = (sec == 8) ? ub1 : (b1 + sec * D_FF);

  // LDS: A buffers [2][8192] @0, B buffers [2][8192] @16384; epilogue overlay 128*136*2
  __shared__ char smem[34816];
  const int tid = threadIdx.x, wave = tid >> 6, lane = tid & 63;
  const int l16 = lane & 15, quad = lane >> 4;
  const int wm = wave & 1, wn = wave >> 1;

  f32x4_t acc[4][4];
#pragma unroll
  for (int i = 0; i < 4; i++)
#pragma unroll
    for (int j = 0; j < 4; j++) acc[i][j] = f32x4_t{0.f, 0.f, 0.f, 0.f};

  // per-wave staging role: waves 0,1 -> A (4KB each), waves 2,3 -> B
  const char* gbase; size_t gstr; char* lbase;
  if (wave < 2) {
    gbase = (const char*)xgp + ((size_t)(groff + mt * 128)) * 64 + wave * 4096 + lane * 16;
    gstr  = (size_t)TROWS * 64;
    lbase = smem + wave * 4096;
  } else {
    gbase = Bbase + (size_t)ft * 128 * 64 + (wave - 2) * 4096 + lane * 16;
    gstr  = (size_t)D_FF * 64;
    lbase = smem + 16384 + (wave - 2) * 4096;
  }

  auto issue = [&](int s) {
    const char* g = gbase + (size_t)s * gstr;
    char* l = lbase + (s & 1) * 8192;
#pragma unroll
    for (int i = 0; i < 4; i++) load_lds16(g + i * 1024, l + i * 1024);
  };
  auto compute = [&](int s) {
    const char* ab = smem + (s & 1) * 8192;
    const char* bb = smem + 16384 + (s & 1) * 8192;
    bf16x8_t af[4], bfr[4];
#pragma unroll
    for (int f = 0; f < 4; f++)
      af[f] = *(const bf16x8_t*)(ab + (wm * 64 + f * 16 + l16) * 64 + quad * 16);
#pragma unroll
    for (int f = 0; f < 4; f++)
      bfr[f] = *(const bf16x8_t*)(bb + (wn * 64 + f * 16 + l16) * 64 + quad * 16);
#pragma unroll
    for (int fm = 0; fm < 4; fm++)
#pragma unroll
      for (int fn = 0; fn < 4; fn++)
        acc[fm][fn] = mfma_bf16(af[fm], bfr[fn], acc[fm][fn]);
  };

  issue(0);
#pragma unroll 2
  for (int s = 0; s < 15; s++) {
    issue(s + 1);          // prefetch into other buffer BEFORE waiting
    WAITCNT4;              // wait only stage-s loads (4 oldest)
    RAWBAR;
    compute(s);
    WAIT_LGKM0;            // ds_reads of buf[s&1] complete before signaling reuse barrier
    RAWBAR;                // all waves done reading buf[s&1] -> next iter may overwrite
  }
  WAITCNT0;
  RAWBAR;
  compute(15);
  __syncthreads();         // all waves done with LDS tiles before epilogue overlay

  // epilogue: bias + exact gelu -> LDS [128][136] bf16 -> hp k-slab
  bf16_t* ep = (bf16_t*)smem;
#pragma unroll
  for (int fm = 0; fm < 4; fm++)
#pragma unroll
    for (int fn = 0; fn < 4; fn++)
#pragma unroll
      for (int i = 0; i < 4; i++) {
        int row = wm * 64 + fm * 16 + quad * 4 + i;
        int col = wn * 64 + fn * 16 + l16;
        float v = acc[fm][fn][i] + bias[ft * 128 + col];
        float gv = 0.5f * v * (1.0f + erff(v * 0.70710678118654752f));
        ep[row * 136 + col] = (bf16_t)gv;
      }
  __syncthreads();
#pragma unroll
  for (int i = 0; i < 2; i++) {
    int id = i * 256 + tid;
    int row = id & 127, cc = id >> 7;
    const uint4* src = (const uint4*)(ep + row * 136 + cc * 32);
    char* dst = (char*)hp + ((size_t)(ft * 4 + cc) * TROWS + groff + mt * 128 + row) * 64;
#pragma unroll
    for (int j = 0; j < 4; j++) ((uint4*)dst)[j] = src[j];
  }
}

// GEMM2: y[rows][512] = h @ W2 + b2, gate-scale, scatter; BK=32 double-buffered
__global__ __launch_bounds__(256) void k_gemm2(
    const bf16_t* __restrict__ hp, const bf16_t* __restrict__ w2p,
    const bf16_t* __restrict__ uw2p,
    const float* __restrict__ b2, const float* __restrict__ ub2,
    const int* __restrict__ soff, const int* __restrict__ spc,
    const int* __restrict__ rmeta, const float* __restrict__ rgate,
    bf16_t* __restrict__ s0, bf16_t* __restrict__ s1, float* __restrict__ out) {
  const int sec = blockIdx.z, mt = blockIdx.x, nt = blockIdx.y;
  if (mt * 128 >= spc[sec]) return;
  const int groff = soff[sec];
  const char* Bbase = (const char*)((sec == 8) ? uw2p : (w2p + (size_t)sec * 64 * D_MODEL * 32));
  const float* bias = (sec == 8) ? ub2 : (b2 + sec * D_MODEL);

  __shared__ char smem[32768];
  const int tid = threadIdx.x, wave = tid >> 6, lane = tid & 63;
  const int l16 = lane & 15, quad = lane >> 4;
  const int wm = wave & 1, wn = wave >> 1;

  f32x4_t acc[4][4];
#pragma unroll
  for (int i = 0; i < 4; i++)
#pragma unroll
    for (int j = 0; j < 4; j++) acc[i][j] = f32x4_t{0.f, 0.f, 0.f, 0.f};

  const char* gbase; size_t gstr; char* lbase;
  if (wave < 2) {
    gbase = (const char*)hp + ((size_t)(groff + mt * 128)) * 64 + wave * 4096 + lane * 16;
    gstr  = (size_t)TROWS * 64;
    lbase = smem + wave * 4096;
  } else {
    gbase = Bbase + (size_t)nt * 128 * 64 + (wave - 2) * 4096 + lane * 16;
    gstr  = (size_t)D_MODEL * 64;
    lbase = smem + 16384 + (wave - 2) * 4096;
  }

  auto issue = [&](int s) {
    const char* g = gbase + (size_t)s * gstr;
    char* l = lbase + (s & 1) * 8192;
#pragma unroll
    for (int i = 0; i < 4; i++) load_lds16(g + i * 1024, l + i * 1024);
  };
  auto compute = [&](int s) {
    const char* ab = smem + (s & 1) * 8192;
    const char* bb = smem + 16384 + (s & 1) * 8192;
    bf16x8_t af[4], bfr[4];
#pragma unroll
    for (int f = 0; f < 4; f++)
      af[f] = *(const bf16x8_t*)(ab + (wm * 64 + f * 16 + l16) * 64 + quad * 16);
#pragma unroll
    for (int f = 0; f < 4; f++)
      bfr[f] = *(const bf16x8_t*)(bb + (wn * 64 + f * 16 + l16) * 64 + quad * 16);
#pragma unroll
    for (int fm = 0; fm < 4; fm++)
#pragma unroll
      for (int fn = 0; fn < 4; fn++)
        acc[fm][fn] = mfma_bf16(af[fm], bfr[fn], acc[fm][fn]);
  };

  issue(0);
#pragma unroll 2
  for (int s = 0; s < 63; s++) {
    issue(s + 1);
    WAITCNT4;
    RAWBAR;
    compute(s);
    WAIT_LGKM0;
    RAWBAR;
  }
  WAITCNT0;
  RAWBAR;
  compute(63);

  // epilogue: +b2, *gate, scatter by slot (registers + global only)
#pragma unroll
  for (int fm = 0; fm < 4; fm++) {
#pragma unroll
    for (int i = 0; i < 4; i++) {
      int grow = groff + mt * 128 + wm * 64 + fm * 16 + quad * 4 + i;
      int meta = rmeta[grow];
      int slot = meta & 3;
      if (slot == 3) continue;
      float g = rgate[grow];
      size_t tkoff = (size_t)(meta >> 2) * D_MODEL;
      if (slot == 2) {
        float* dst = out + tkoff;
#pragma unroll
        for (int fn = 0; fn < 4; fn++) {
          int d = nt * 128 + wn * 64 + fn * 16 + l16;
          dst[d] = (acc[fm][fn][i] + bias[d]) * g;
        }
      } else {
        bf16_t* dst = (slot ? s1 : s0) + tkoff;
#pragma unroll
        for (int fn = 0; fn < 4; fn++) {
          int d = nt * 128 + wn * 64 + fn * 16 + l16;
          dst[d] = (bf16_t)((acc[fm][fn][i] + bias[d]) * g);
        }
      }
    }
  }
}

__global__ void k_combine(const bf16x4_t* __restrict__ s0, const bf16x4_t* __restrict__ s1,
                          float4* __restrict__ out, int n4) {
  int i = blockIdx.x * blockDim.x + threadIdx.x;
  if (i >= n4) return;
  bf16x4_t a = s0[i], b = s1[i];
  float4 o = out[i];
  o.x += (float)a[0] + (float)b[0];
  o.y += (float)a[1] + (float)b[1];
  o.z += (float)a[2] + (float)b[2];
  o.w += (float)a[3] + (float)b[3];
  out[i] = o;
}

extern "C" void kernel_launch(void* const* d_in, const int* in_sizes, int n_in,
                              void* d_out, int out_size, void* d_ws, size_t ws_size,
                              hipStream_t stream) {
  (void)in_sizes; (void)n_in; (void)out_size; (void)ws_size;
  const float* x        = (const float*)d_in[0];
  const int*   task_ids = (const int*)  d_in[1];
  const float* task_emb = (const float*)d_in[2];
  const float* gate_w   = (const float*)d_in[3];
  const float* gate_b   = (const float*)d_in[4];
  const float* w1       = (const float*)d_in[5];
  const float* b1       = (const float*)d_in[6];
  const float* w2       = (const float*)d_in[7];
  const float* b2       = (const float*)d_in[8];
  const float* uw1      = (const float*)d_in[9];
  const float* ub1      = (const float*)d_in[10];
  const float* uw2      = (const float*)d_in[11];
  const float* ub2      = (const float*)d_in[12];

  char* ws = (char*)d_ws;
  bf16_t* w1p   = (bf16_t*)(ws + W1P_OFF);
  bf16_t* uw1p  = (bf16_t*)(ws + UW1P_OFF);
  bf16_t* w2p   = (bf16_t*)(ws + W2P_OFF);
  bf16_t* uw2p  = (bf16_t*)(ws + UW2P_OFF);
  bf16_t* s0    = (bf16_t*)(ws + S0_OFF);
  bf16_t* s1    = (bf16_t*)(ws + S1_OFF);
  int*    cnts  = (int*)   (ws + CNT_OFF);
  int*    tokl  = (int*)   (ws + TOKL_OFF);
  float*  gatel = (float*) (ws + GATEL_OFF);
  float*  omg   = (float*) (ws + OMEGA_OFF);
  double* tlog  = (double*)(ws + TLOG_OFF);
  int*    soff  = (int*)   (ws + SOFF_OFF);
  int*    spc   = (int*)   (ws + SPC_OFF);
  int*    rmeta = (int*)   (ws + RMETA_OFF);
  float*  rgate = (float*) (ws + RGATE_OFF);
  bf16_t* xgp   = (bf16_t*)(ws + XGP_OFF);
  bf16_t* hp    = (bf16_t*)(ws + HP_OFF);

  float* out    = (float*)d_out;
  float* logits = out + (size_t)TOKENS * D_MODEL;

  hipMemsetAsync(cnts, 0, 64, stream);

  k_pack<<<dim3(32, 8, NEXP), 256, 0, stream>>>(w1, w1p, D_MODEL, D_FF);
  k_pack<<<dim3(8, 32, NEXP), 256, 0, stream>>>(w2, w2p, D_FF, D_MODEL);
  k_pack<<<dim3(32, 8, 1),    256, 0, stream>>>(uw1, uw1p, D_MODEL, D_FF);
  k_pack<<<dim3(8, 32, 1),    256, 0, stream>>>(uw2, uw2p, D_FF, D_MODEL);
  k_tlog<<<1, 64, 0, stream>>>(task_ids, task_emb, gate_w, gate_b, tlog);
  k_gate<<<dim3(TOKENS / 4), 256, 0, stream>>>(x, gate_w, tlog, logits, cnts, tokl, gatel, omg);
  k_soff<<<1, 64, 0, stream>>>(cnts, soff, spc);
  k_fill<<<dim3((TROWS + 255) / 256), 256, 0, stream>>>(cnts, soff, spc, tokl, gatel, omg,
                                                        rmeta, rgate);
  k_gather<<<dim3(TROWS / 128), 256, 0, stream>>>(x, rmeta, xgp);
  k_gemm1<<<dim3(64, 16, 9), 256, 0, stream>>>(xgp, w1p, uw1p, b1, ub1, soff, spc, hp);
  k_gemm2<<<dim3(64, 4, 9), 256, 0, stream>>>(hp, w2p, uw2p, b2, ub2, soff, spc,
                                              rmeta, rgate, s0, s1, out);
  const int n4 = TOKENS * D_MODEL / 4;
  k_combine<<<dim3(n4 / 256), 256, 0, stream>>>((const bf16x4_t*)s0, (const bf16x4_t*)s1,
                                                (float4*)out, n4);
}

// Round 6
// 492.283 us; speedup vs baseline: 1.5505x; 1.3521x over previous
//
#include <hip/hip_runtime.h>

#define D_MODEL 512
#define D_FF    2048
#define NEXP    8
#define TOKENS  8192
#define TROWS   25600     // 8192 universal + 16384 expert slots + padding

typedef __bf16 bf16_t;
typedef __attribute__((ext_vector_type(8))) __bf16 bf16x8_t;
typedef __attribute__((ext_vector_type(4))) __bf16 bf16x4_t;
typedef __attribute__((ext_vector_type(4))) float  f32x4_t;

// ---- workspace layout (bytes) ----
#define W1P_OFF    0u            // bf16 [8][16][2048][32]   k-slab pack of w1
#define UW1P_OFF   16777216u     // bf16 [16][2048][32]
#define W2P_OFF    18874368u     // bf16 [8][64][512][32]
#define UW2P_OFF   35651584u     // bf16 [64][512][32]
#define S0_OFF     37748736u     // bf16 [8192][512]
#define S1_OFF     46137344u     // bf16 [8192][512]
#define CNT_OFF    54525952u     // int[16]
#define TOKL_OFF   54526016u     // int  [8][8192]  entry=(token<<1)|slot
#define GATEL_OFF  54788160u     // float[8][8192]
#define OMEGA_OFF  55050304u     // float[8192]
#define TLOG_OFF   55083072u     // double[8][8]
#define SOFF_OFF   55083584u     // int[16] section row offsets
#define SPC_OFF    55083648u     // int[16] section padded counts
#define RMETA_OFF  55083712u     // int[25600]  (tok<<2)|slot; slot 0/1 expert,2 univ,3 pad
#define RGATE_OFF  55186112u     // float[25600]
#define XGP_OFF    55288512u     // bf16 [16][25600][32]  k-slab gathered X
#define HP_OFF     81502912u     // bf16 [64][25600][32]  k-slab h
#define TOKE_OFF   186360512u    // int[8192]   packed e0 | e1<<8
#define TG_OFF     186393280u    // float2[8192] g0,g1

__device__ inline f32x4_t mfma_bf16(bf16x8_t a, bf16x8_t b, f32x4_t c) {
  return __builtin_amdgcn_mfma_f32_16x16x32_bf16(a, b, c, 0, 0, 0);
}

__device__ __forceinline__ void load_lds16(const void* g, void* l) {
  __builtin_amdgcn_global_load_lds(
      (const __attribute__((address_space(1))) unsigned int*)g,
      (__attribute__((address_space(3))) unsigned int*)l, 16, 0, 0);
}

#define WAITCNT4   asm volatile("s_waitcnt vmcnt(4)" ::: "memory")
#define WAITCNT0   asm volatile("s_waitcnt vmcnt(0)" ::: "memory")
#define WAIT_LGKM0 asm volatile("s_waitcnt lgkmcnt(0)" ::: "memory")
#define RAWBAR     asm volatile("s_barrier" ::: "memory")

// pack in[R][C] f32 -> out[R/32][C][32] bf16   (out[s][c][j] = in[s*32+j][c])
__global__ void k_pack(const float* __restrict__ in, bf16_t* __restrict__ out, int R, int C) {
  __shared__ float tile[64][65];
  const size_t mat = (size_t)blockIdx.z * R * C;
  in  += mat;
  out += mat;
  int r0 = blockIdx.y * 64, c0 = blockIdx.x * 64;
  for (int i = threadIdx.x; i < 4096; i += 256) {
    int r = i >> 6, c = i & 63;
    tile[r][c] = in[(size_t)(r0 + r) * C + c0 + c];
  }
  __syncthreads();
  int item = threadIdx.x >> 1, jh = threadIdx.x & 1;
  int c = item & 63, s = item >> 6;
  union { bf16_t h[16]; uint4 u[2]; } t;
#pragma unroll
  for (int k = 0; k < 16; k++) t.h[k] = (bf16_t)tile[s * 32 + jh * 16 + k][c];
  char* dst = (char*)out + ((size_t)((r0 >> 5) + s) * C + (c0 + c)) * 64 + jh * 32;
  ((uint4*)dst)[0] = t.u[0];
  ((uint4*)dst)[1] = t.u[1];
}

__global__ void k_tlog(const int* __restrict__ task_ids, const float* __restrict__ task_emb,
                       const float* __restrict__ gate_w, const float* __restrict__ gate_b,
                       double* __restrict__ tlog) {
  int i = threadIdx.x;
  if (i >= 64) return;
  int b = i >> 3, e = i & 7;
  const float* te = task_emb + (size_t)task_ids[b] * D_MODEL;
  double acc = (double)gate_b[e];
  for (int d = 0; d < D_MODEL; d++)
    acc += (double)te[d] * (double)gate_w[(size_t)(D_MODEL + d) * NEXP + e];
  tlog[i] = acc;
}

// one wave per token: f64 logits, top-2 softmax. NO global atomics here.
__global__ void k_gate(const float* __restrict__ x, const float* __restrict__ gate_w,
                       const double* __restrict__ tlog,
                       float* __restrict__ logits_out,
                       int* __restrict__ toke, float2* __restrict__ tg,
                       float* __restrict__ omega) {
  int gtid = blockIdx.x * blockDim.x + threadIdx.x;
  int t = gtid >> 6;
  int lane = gtid & 63;
  if (t >= TOKENS) return;
  const float* xr = x + (size_t)t * D_MODEL;
  int d0 = lane * 8;
  float4 xa = *(const float4*)(xr + d0);
  float4 xc = *(const float4*)(xr + d0 + 4);
  float xv[8] = {xa.x, xa.y, xa.z, xa.w, xc.x, xc.y, xc.z, xc.w};
  double acc[NEXP];
#pragma unroll
  for (int e = 0; e < NEXP; e++) acc[e] = 0.0;
#pragma unroll
  for (int j = 0; j < 8; j++) {
    const float* gwr = gate_w + (size_t)(d0 + j) * NEXP;
    float4 g0 = *(const float4*)gwr;
    float4 g1 = *(const float4*)(gwr + 4);
    double xd = (double)xv[j];
    acc[0] += xd * (double)g0.x; acc[1] += xd * (double)g0.y;
    acc[2] += xd * (double)g0.z; acc[3] += xd * (double)g0.w;
    acc[4] += xd * (double)g1.x; acc[5] += xd * (double)g1.y;
    acc[6] += xd * (double)g1.z; acc[7] += xd * (double)g1.w;
  }
#pragma unroll
  for (int off = 32; off > 0; off >>= 1) {
#pragma unroll
    for (int e = 0; e < NEXP; e++) acc[e] += __shfl_xor(acc[e], off);
  }
  if (lane == 0) {
    int b = t >> 10;
    double lg[NEXP];
#pragma unroll
    for (int e = 0; e < NEXP; e++) {
      lg[e] = acc[e] + tlog[b * NEXP + e];
      logits_out[(size_t)t * NEXP + e] = (float)lg[e];
    }
    int e0 = 0;
    for (int e = 1; e < NEXP; e++) if (lg[e] > lg[e0]) e0 = e;   // first idx wins ties
    int e1 = (e0 == 0) ? 1 : 0;
    for (int e = 0; e < NEXP; e++) if (e != e0 && lg[e] > lg[e1]) e1 = e;
    double p0 = 1.0 / (1.0 + exp(lg[e1] - lg[e0]));
    float g0f = (float)p0;
    float g1f = (float)(1.0 - p0);
    omega[t] = 1.0f - g0f;
    toke[t] = e0 | (e1 << 8);
    tg[t] = float2{g0f, g1f};
  }
}

// two-level routing: LDS ranks + 8 global atomics per block (256 total)
__global__ void k_route(const int* __restrict__ toke, const float2* __restrict__ tg,
                        int* __restrict__ counts, int* __restrict__ tokl,
                        float* __restrict__ gatel) {
  __shared__ int lcnt[NEXP];
  __shared__ int lbase[NEXP];
  const int tid = threadIdx.x;
  if (tid < NEXP) lcnt[tid] = 0;
  __syncthreads();
  const int t = blockIdx.x * 256 + tid;
  const int pe = toke[t];
  const int e0 = pe & 0xff, e1 = pe >> 8;
  const float2 g = tg[t];
  const int r0 = atomicAdd(&lcnt[e0], 1);
  const int r1 = atomicAdd(&lcnt[e1], 1);
  __syncthreads();
  if (tid < NEXP) lbase[tid] = atomicAdd(counts + tid, lcnt[tid]);
  __syncthreads();
  int i0 = lbase[e0] + r0;
  tokl[e0 * TOKENS + i0]  = (t << 1);
  gatel[e0 * TOKENS + i0] = g.x;
  int i1 = lbase[e1] + r1;
  tokl[e1 * TOKENS + i1]  = (t << 1) | 1;
  gatel[e1 * TOKENS + i1] = g.y;
}

// tiny: section offsets from counts
__global__ void k_soff(const int* __restrict__ cnts, int* __restrict__ soff, int* __restrict__ spc) {
  if (threadIdx.x == 0) {
    soff[8] = 0; spc[8] = TOKENS;
    int off = TOKENS;
    for (int e = 0; e < 8; e++) {
      int c = cnts[e];
      int p = (c + 127) & ~127;
      soff[e] = off; spc[e] = p;
      off += p;
    }
  }
}

// parallel row-metadata fill
__global__ void k_fill(const int* __restrict__ cnts, const int* __restrict__ soff,
                       const int* __restrict__ spc,
                       const int* __restrict__ tokl, const float* __restrict__ gatel,
                       const float* __restrict__ omega,
                       int* __restrict__ rmeta, float* __restrict__ rgate) {
  int r = blockIdx.x * 256 + threadIdx.x;
  if (r >= TROWS) return;
  if (r < TOKENS) { rmeta[r] = (r << 2) | 2; rgate[r] = omega[r]; return; }
  int meta = 3; float g = 0.f;
#pragma unroll
  for (int e = 0; e < 8; e++) {
    int off = soff[e];
    if (r >= off && r < off + spc[e]) {
      int i = r - off;
      if (i < cnts[e]) {
        int en = tokl[e * TOKENS + i];
        meta = ((en >> 1) << 2) | (en & 1);
        g = gatel[e * TOKENS + i];
      }
      break;
    }
  }
  rmeta[r] = meta; rgate[r] = g;
}

// gather X rows (f32 -> bf16) into k-slab layout xgp[s][row][32]
__global__ void k_gather(const float* __restrict__ x, const int* __restrict__ rmeta,
                         bf16_t* __restrict__ xgp) {
  int rbase = blockIdx.x * 128;
  for (int it = 0; it < 8; it++) {
    int id = it * 256 + threadIdx.x;
    int row = rbase + (id >> 4), s = id & 15;
    int meta = rmeta[row];
    union { bf16_t h[32]; uint4 u[4]; } t;
    if ((meta & 3) == 3) {
#pragma unroll
      for (int j = 0; j < 4; j++) t.u[j] = uint4{0, 0, 0, 0};
    } else {
      const float* src = x + (size_t)(meta >> 2) * D_MODEL + s * 32;
#pragma unroll
      for (int j = 0; j < 32; j += 4) {
        float4 v = *(const float4*)(src + j);
        t.h[j] = (bf16_t)v.x; t.h[j + 1] = (bf16_t)v.y;
        t.h[j + 2] = (bf16_t)v.z; t.h[j + 3] = (bf16_t)v.w;
      }
    }
    char* dst = (char*)xgp + ((size_t)s * TROWS + row) * 64;
#pragma unroll
    for (int j = 0; j < 4; j++) ((uint4*)dst)[j] = t.u[j];
  }
}

// GEMM1: h[rows][2048] = gelu(Xg @ W1 + b1); BK=32, double-buffered raw-barrier pipeline
__global__ __launch_bounds__(256) void k_gemm1(
    const bf16_t* __restrict__ xgp, const bf16_t* __restrict__ w1p,
    const bf16_t* __restrict__ uw1p,
    const float* __restrict__ b1, const float* __restrict__ ub1,
    const int* __restrict__ soff, const int* __restrict__ spc,
    bf16_t* __restrict__ hp) {
  const int sec = blockIdx.z, mt = blockIdx.x, ft = blockIdx.y;
  if (mt * 128 >= spc[sec]) return;
  const int groff = soff[sec];
  const char* Bbase = (const char*)((sec == 8) ? uw1p : (w1p + (size_t)sec * 16 * D_FF * 32));
  const float* bias = (sec == 8) ? ub1 : (b1 + sec * D_FF);

  // LDS: A buffers [2][8192] @0, B buffers [2][8192] @16384; epilogue overlay 128*136*2
  __shared__ char smem[34816];
  const int tid = threadIdx.x, wave = tid >> 6, lane = tid & 63;
  const int l16 = lane & 15, quad = lane >> 4;
  const int wm = wave & 1, wn = wave >> 1;

  f32x4_t acc[4][4];
#pragma unroll
  for (int i = 0; i < 4; i++)
#pragma unroll
    for (int j = 0; j < 4; j++) acc[i][j] = f32x4_t{0.f, 0.f, 0.f, 0.f};

  // per-wave staging role: waves 0,1 -> A (4KB each), waves 2,3 -> B
  const char* gbase; size_t gstr; char* lbase;
  if (wave < 2) {
    gbase = (const char*)xgp + ((size_t)(groff + mt * 128)) * 64 + wave * 4096 + lane * 16;
    gstr  = (size_t)TROWS * 64;
    lbase = smem + wave * 4096;
  } else {
    gbase = Bbase + (size_t)ft * 128 * 64 + (wave - 2) * 4096 + lane * 16;
    gstr  = (size_t)D_FF * 64;
    lbase = smem + 16384 + (wave - 2) * 4096;
  }

  auto issue = [&](int s) {
    const char* g = gbase + (size_t)s * gstr;
    char* l = lbase + (s & 1) * 8192;
#pragma unroll
    for (int i = 0; i < 4; i++) load_lds16(g + i * 1024, l + i * 1024);
  };
  auto compute = [&](int s) {
    const char* ab = smem + (s & 1) * 8192;
    const char* bb = smem + 16384 + (s & 1) * 8192;
    bf16x8_t af[4], bfr[4];
#pragma unroll
    for (int f = 0; f < 4; f++)
      af[f] = *(const bf16x8_t*)(ab + (wm * 64 + f * 16 + l16) * 64 + quad * 16);
#pragma unroll
    for (int f = 0; f < 4; f++)
      bfr[f] = *(const bf16x8_t*)(bb + (wn * 64 + f * 16 + l16) * 64 + quad * 16);
#pragma unroll
    for (int fm = 0; fm < 4; fm++)
#pragma unroll
      for (int fn = 0; fn < 4; fn++)
        acc[fm][fn] = mfma_bf16(af[fm], bfr[fn], acc[fm][fn]);
  };

  issue(0);
#pragma unroll 2
  for (int s = 0; s < 15; s++) {
    issue(s + 1);          // prefetch into other buffer BEFORE waiting
    WAITCNT4;              // wait only stage-s loads (4 oldest)
    RAWBAR;
    compute(s);
    WAIT_LGKM0;            // ds_reads of buf[s&1] complete before signaling reuse barrier
    RAWBAR;                // all waves done reading buf[s&1] -> next iter may overwrite
  }
  WAITCNT0;
  RAWBAR;
  compute(15);
  __syncthreads();         // all waves done with LDS tiles before epilogue overlay

  // epilogue: bias + exact gelu -> LDS [128][136] bf16 -> hp k-slab
  bf16_t* ep = (bf16_t*)smem;
#pragma unroll
  for (int fm = 0; fm < 4; fm++)
#pragma unroll
    for (int fn = 0; fn < 4; fn++)
#pragma unroll
      for (int i = 0; i < 4; i++) {
        int row = wm * 64 + fm * 16 + quad * 4 + i;
        int col = wn * 64 + fn * 16 + l16;
        float v = acc[fm][fn][i] + bias[ft * 128 + col];
        float gv = 0.5f * v * (1.0f + erff(v * 0.70710678118654752f));
        ep[row * 136 + col] = (bf16_t)gv;
      }
  __syncthreads();
#pragma unroll
  for (int i = 0; i < 2; i++) {
    int id = i * 256 + tid;
    int row = id & 127, cc = id >> 7;
    const uint4* src = (const uint4*)(ep + row * 136 + cc * 32);
    char* dst = (char*)hp + ((size_t)(ft * 4 + cc) * TROWS + groff + mt * 128 + row) * 64;
#pragma unroll
    for (int j = 0; j < 4; j++) ((uint4*)dst)[j] = src[j];
  }
}

// GEMM2: y[rows][512] = h @ W2 + b2, gate-scale, scatter; BK=32 double-buffered
__global__ __launch_bounds__(256) void k_gemm2(
    const bf16_t* __restrict__ hp, const bf16_t* __restrict__ w2p,
    const bf16_t* __restrict__ uw2p,
    const float* __restrict__ b2, const float* __restrict__ ub2,
    const int* __restrict__ soff, const int* __restrict__ spc,
    const int* __restrict__ rmeta, const float* __restrict__ rgate,
    bf16_t* __restrict__ s0, bf16_t* __restrict__ s1, float* __restrict__ out) {
  const int sec = blockIdx.z, mt = blockIdx.x, nt = blockIdx.y;
  if (mt * 128 >= spc[sec]) return;
  const int groff = soff[sec];
  const char* Bbase = (const char*)((sec == 8) ? uw2p : (w2p + (size_t)sec * 64 * D_MODEL * 32));
  const float* bias = (sec == 8) ? ub2 : (b2 + sec * D_MODEL);

  __shared__ char smem[32768];
  const int tid = threadIdx.x, wave = tid >> 6, lane = tid & 63;
  const int l16 = lane & 15, quad = lane >> 4;
  const int wm = wave & 1, wn = wave >> 1;

  f32x4_t acc[4][4];
#pragma unroll
  for (int i = 0; i < 4; i++)
#pragma unroll
    for (int j = 0; j < 4; j++) acc[i][j] = f32x4_t{0.f, 0.f, 0.f, 0.f};

  const char* gbase; size_t gstr; char* lbase;
  if (wave < 2) {
    gbase = (const char*)hp + ((size_t)(groff + mt * 128)) * 64 + wave * 4096 + lane * 16;
    gstr  = (size_t)TROWS * 64;
    lbase = smem + wave * 4096;
  } else {
    gbase = Bbase + (size_t)nt * 128 * 64 + (wave - 2) * 4096 + lane * 16;
    gstr  = (size_t)D_MODEL * 64;
    lbase = smem + 16384 + (wave - 2) * 4096;
  }

  auto issue = [&](int s) {
    const char* g = gbase + (size_t)s * gstr;
    char* l = lbase + (s & 1) * 8192;
#pragma unroll
    for (int i = 0; i < 4; i++) load_lds16(g + i * 1024, l + i * 1024);
  };
  auto compute = [&](int s) {
    const char* ab = smem + (s & 1) * 8192;
    const char* bb = smem + 16384 + (s & 1) * 8192;
    bf16x8_t af[4], bfr[4];
#pragma unroll
    for (int f = 0; f < 4; f++)
      af[f] = *(const bf16x8_t*)(ab + (wm * 64 + f * 16 + l16) * 64 + quad * 16);
#pragma unroll
    for (int f = 0; f < 4; f++)
      bfr[f] = *(const bf16x8_t*)(bb + (wn * 64 + f * 16 + l16) * 64 + quad * 16);
#pragma unroll
    for (int fm = 0; fm < 4; fm++)
#pragma unroll
      for (int fn = 0; fn < 4; fn++)
        acc[fm][fn] = mfma_bf16(af[fm], bfr[fn], acc[fm][fn]);
  };

  issue(0);
#pragma unroll 2
  for (int s = 0; s < 63; s++) {
    issue(s + 1);
    WAITCNT4;
    RAWBAR;
    compute(s);
    WAIT_LGKM0;
    RAWBAR;
  }
  WAITCNT0;
  RAWBAR;
  compute(63);

  // epilogue: +b2, *gate, scatter by slot (registers + global only)
#pragma unroll
  for (int fm = 0; fm < 4; fm++) {
#pragma unroll
    for (int i = 0; i < 4; i++) {
      int grow = groff + mt * 128 + wm * 64 + fm * 16 + quad * 4 + i;
      int meta = rmeta[grow];
      int slot = meta & 3;
      if (slot == 3) continue;
      float g = rgate[grow];
      size_t tkoff = (size_t)(meta >> 2) * D_MODEL;
      if (slot == 2) {
        float* dst = out + tkoff;
#pragma unroll
        for (int fn = 0; fn < 4; fn++) {
          int d = nt * 128 + wn * 64 + fn * 16 + l16;
          dst[d] = (acc[fm][fn][i] + bias[d]) * g;
        }
      } else {
        bf16_t* dst = (slot ? s1 : s0) + tkoff;
#pragma unroll
        for (int fn = 0; fn < 4; fn++) {
          int d = nt * 128 + wn * 64 + fn * 16 + l16;
          dst[d] = (bf16_t)((acc[fm][fn][i] + bias[d]) * g);
        }
      }
    }
  }
}

__global__ void k_combine(const bf16x4_t* __restrict__ s0, const bf16x4_t* __restrict__ s1,
                          float4* __restrict__ out, int n4) {
  int i = blockIdx.x * blockDim.x + threadIdx.x;
  if (i >= n4) return;
  bf16x4_t a = s0[i], b = s1[i];
  float4 o = out[i];
  o.x += (float)a[0] + (float)b[0];
  o.y += (float)a[1] + (float)b[1];
  o.z += (float)a[2] + (float)b[2];
  o.w += (float)a[3] + (float)b[3];
  out[i] = o;
}

extern "C" void kernel_launch(void* const* d_in, const int* in_sizes, int n_in,
                              void* d_out, int out_size, void* d_ws, size_t ws_size,
                              hipStream_t stream) {
  (void)in_sizes; (void)n_in; (void)out_size; (void)ws_size;
  const float* x        = (const float*)d_in[0];
  const int*   task_ids = (const int*)  d_in[1];
  const float* task_emb = (const float*)d_in[2];
  const float* gate_w   = (const float*)d_in[3];
  const float* gate_b   = (const float*)d_in[4];
  const float* w1       = (const float*)d_in[5];
  const float* b1       = (const float*)d_in[6];
  const float* w2       = (const float*)d_in[7];
  const float* b2       = (const float*)d_in[8];
  const float* uw1      = (const float*)d_in[9];
  const float* ub1      = (const float*)d_in[10];
  const float* uw2      = (const float*)d_in[11];
  const float* ub2      = (const float*)d_in[12];

  char* ws = (char*)d_ws;
  bf16_t* w1p   = (bf16_t*)(ws + W1P_OFF);
  bf16_t* uw1p  = (bf16_t*)(ws + UW1P_OFF);
  bf16_t* w2p   = (bf16_t*)(ws + W2P_OFF);
  bf16_t* uw2p  = (bf16_t*)(ws + UW2P_OFF);
  bf16_t* s0    = (bf16_t*)(ws + S0_OFF);
  bf16_t* s1    = (bf16_t*)(ws + S1_OFF);
  int*    cnts  = (int*)   (ws + CNT_OFF);
  int*    tokl  = (int*)   (ws + TOKL_OFF);
  float*  gatel = (float*) (ws + GATEL_OFF);
  float*  omg   = (float*) (ws + OMEGA_OFF);
  double* tlog  = (double*)(ws + TLOG_OFF);
  int*    soff  = (int*)   (ws + SOFF_OFF);
  int*    spc   = (int*)   (ws + SPC_OFF);
  int*    rmeta = (int*)   (ws + RMETA_OFF);
  float*  rgate = (float*) (ws + RGATE_OFF);
  bf16_t* xgp   = (bf16_t*)(ws + XGP_OFF);
  bf16_t* hp    = (bf16_t*)(ws + HP_OFF);
  int*    toke  = (int*)   (ws + TOKE_OFF);
  float2* tg    = (float2*)(ws + TG_OFF);

  float* out    = (float*)d_out;
  float* logits = out + (size_t)TOKENS * D_MODEL;

  hipMemsetAsync(cnts, 0, 64, stream);

  k_pack<<<dim3(32, 8, NEXP), 256, 0, stream>>>(w1, w1p, D_MODEL, D_FF);
  k_pack<<<dim3(8, 32, NEXP), 256, 0, stream>>>(w2, w2p, D_FF, D_MODEL);
  k_pack<<<dim3(32, 8, 1),    256, 0, stream>>>(uw1, uw1p, D_MODEL, D_FF);
  k_pack<<<dim3(8, 32, 1),    256, 0, stream>>>(uw2, uw2p, D_FF, D_MODEL);
  k_tlog<<<1, 64, 0, stream>>>(task_ids, task_emb, gate_w, gate_b, tlog);
  k_gate<<<dim3(TOKENS / 4), 256, 0, stream>>>(x, gate_w, tlog, logits, toke, tg, omg);
  k_route<<<dim3(TOKENS / 256), 256, 0, stream>>>(toke, tg, cnts, tokl, gatel);
  k_soff<<<1, 64, 0, stream>>>(cnts, soff, spc);
  k_fill<<<dim3((TROWS + 255) / 256), 256, 0, stream>>>(cnts, soff, spc, tokl, gatel, omg,
                                                        rmeta, rgate);
  k_gather<<<dim3(TROWS / 128), 256, 0, stream>>>(x, rmeta, xgp);
  k_gemm1<<<dim3(64, 16, 9), 256, 0, stream>>>(xgp, w1p, uw1p, b1, ub1, soff, spc, hp);
  k_gemm2<<<dim3(64, 4, 9), 256, 0, stream>>>(hp, w2p, uw2p, b2, ub2, soff, spc,
                                              rmeta, rgate, s0, s1, out);
  const int n4 = TOKENS * D_MODEL / 4;
  k_combine<<<dim3(n4 / 256), 256, 0, stream>>>((const bf16x4_t*)s0, (const bf16x4_t*)s1,
                                                (float4*)out, n4);
}

// Round 7
// 471.983 us; speedup vs baseline: 1.6172x; 1.0430x over previous
//
#include <hip/hip_runtime.h>

#define D_MODEL 512
#define D_FF    2048
#define NEXP    8
#define TOKENS  8192
#define TROWS   25600     // 8192 universal + 16384 expert slots + padding

typedef __bf16 bf16_t;
typedef __attribute__((ext_vector_type(8))) __bf16 bf16x8_t;
typedef __attribute__((ext_vector_type(4))) __bf16 bf16x4_t;
typedef __attribute__((ext_vector_type(4))) float  f32x4_t;

// ---- workspace layout (bytes) ----
#define W1P_OFF    0u            // bf16 [8][16][2048][32]   k-slab pack of w1
#define UW1P_OFF   16777216u     // bf16 [16][2048][32]
#define W2P_OFF    18874368u     // bf16 [8][64][512][32]
#define UW2P_OFF   35651584u     // bf16 [64][512][32]
#define S0_OFF     37748736u     // bf16 [8192][512]
#define S1_OFF     46137344u     // bf16 [8192][512]
#define CNT_OFF    54525952u     // int[16]
#define TOKL_OFF   54526016u     // int  [8][8192]  entry=(token<<1)|slot
#define GATEL_OFF  54788160u     // float[8][8192]
#define OMEGA_OFF  55050304u     // float[8192]
#define TLOG_OFF   55083072u     // double[8][8]
#define SOFF_OFF   55083584u     // int[16] section row offsets
#define SPC_OFF    55083648u     // int[16] section padded counts
#define RMETA_OFF  55083712u     // int[25600]  (tok<<2)|slot; slot 0/1 expert,2 univ,3 pad
#define RGATE_OFF  55186112u     // float[25600]
#define XGP_OFF    55288512u     // bf16 [16][25600][32]  k-slab gathered X
#define HP_OFF     81502912u     // bf16 [64][25600][32]  k-slab h
#define TOKE_OFF   186360512u    // int[8192]   packed e0 | e1<<8
#define TG_OFF     186393280u    // float2[8192] g0,g1

__device__ inline f32x4_t mfma_bf16(bf16x8_t a, bf16x8_t b, f32x4_t c) {
  return __builtin_amdgcn_mfma_f32_16x16x32_bf16(a, b, c, 0, 0, 0);
}

__device__ __forceinline__ void load_lds16(const void* g, void* l) {
  __builtin_amdgcn_global_load_lds(
      (const __attribute__((address_space(1))) unsigned int*)g,
      (__attribute__((address_space(3))) unsigned int*)l, 16, 0, 0);
}

// fast gelu: 0.5x(1+tanh(0.79788456(x+0.044715x^3))); max abs err ~3e-4 << bf16 quantum
__device__ __forceinline__ float fast_gelu(float x) {
  float z = 0.7978845608f * (x + 0.044715f * x * x * x);
  float u = __expf(2.0f * z);                 // v_exp_f32 based
  float th = (u - 1.0f) * __builtin_amdgcn_rcpf(u + 1.0f);
  return 0.5f * x * (1.0f + th);
}

#define WAITCNT8   asm volatile("s_waitcnt vmcnt(8)" ::: "memory")
#define WAITCNT4   asm volatile("s_waitcnt vmcnt(4)" ::: "memory")
#define WAITCNT0   asm volatile("s_waitcnt vmcnt(0)" ::: "memory")
#define WAIT_LGKM0 asm volatile("s_waitcnt lgkmcnt(0)" ::: "memory")
#define RAWBAR     asm volatile("s_barrier" ::: "memory")

// pack in[R][C] f32 -> out[R/32][C][32] bf16   (out[s][c][j] = in[s*32+j][c])
__global__ void k_pack(const float* __restrict__ in, bf16_t* __restrict__ out, int R, int C) {
  __shared__ float tile[64][65];
  const size_t mat = (size_t)blockIdx.z * R * C;
  in  += mat;
  out += mat;
  int r0 = blockIdx.y * 64, c0 = blockIdx.x * 64;
  for (int i = threadIdx.x; i < 4096; i += 256) {
    int r = i >> 6, c = i & 63;
    tile[r][c] = in[(size_t)(r0 + r) * C + c0 + c];
  }
  __syncthreads();
  int item = threadIdx.x >> 1, jh = threadIdx.x & 1;
  int c = item & 63, s = item >> 6;
  union { bf16_t h[16]; uint4 u[2]; } t;
#pragma unroll
  for (int k = 0; k < 16; k++) t.h[k] = (bf16_t)tile[s * 32 + jh * 16 + k][c];
  char* dst = (char*)out + ((size_t)((r0 >> 5) + s) * C + (c0 + c)) * 64 + jh * 32;
  ((uint4*)dst)[0] = t.u[0];
  ((uint4*)dst)[1] = t.u[1];
}

__global__ void k_tlog(const int* __restrict__ task_ids, const float* __restrict__ task_emb,
                       const float* __restrict__ gate_w, const float* __restrict__ gate_b,
                       double* __restrict__ tlog) {
  int i = threadIdx.x;
  if (i >= 64) return;
  int b = i >> 3, e = i & 7;
  const float* te = task_emb + (size_t)task_ids[b] * D_MODEL;
  double acc = (double)gate_b[e];
  for (int d = 0; d < D_MODEL; d++)
    acc += (double)te[d] * (double)gate_w[(size_t)(D_MODEL + d) * NEXP + e];
  tlog[i] = acc;
}

// one wave per token: f64 logits, top-2 softmax. NO global atomics here.
__global__ void k_gate(const float* __restrict__ x, const float* __restrict__ gate_w,
                       const double* __restrict__ tlog,
                       float* __restrict__ logits_out,
                       int* __restrict__ toke, float2* __restrict__ tg,
                       float* __restrict__ omega) {
  int gtid = blockIdx.x * blockDim.x + threadIdx.x;
  int t = gtid >> 6;
  int lane = gtid & 63;
  if (t >= TOKENS) return;
  const float* xr = x + (size_t)t * D_MODEL;
  int d0 = lane * 8;
  float4 xa = *(const float4*)(xr + d0);
  float4 xc = *(const float4*)(xr + d0 + 4);
  float xv[8] = {xa.x, xa.y, xa.z, xa.w, xc.x, xc.y, xc.z, xc.w};
  double acc[NEXP];
#pragma unroll
  for (int e = 0; e < NEXP; e++) acc[e] = 0.0;
#pragma unroll
  for (int j = 0; j < 8; j++) {
    const float* gwr = gate_w + (size_t)(d0 + j) * NEXP;
    float4 g0 = *(const float4*)gwr;
    float4 g1 = *(const float4*)(gwr + 4);
    double xd = (double)xv[j];
    acc[0] += xd * (double)g0.x; acc[1] += xd * (double)g0.y;
    acc[2] += xd * (double)g0.z; acc[3] += xd * (double)g0.w;
    acc[4] += xd * (double)g1.x; acc[5] += xd * (double)g1.y;
    acc[6] += xd * (double)g1.z; acc[7] += xd * (double)g1.w;
  }
#pragma unroll
  for (int off = 32; off > 0; off >>= 1) {
#pragma unroll
    for (int e = 0; e < NEXP; e++) acc[e] += __shfl_xor(acc[e], off);
  }
  if (lane == 0) {
    int b = t >> 10;
    double lg[NEXP];
#pragma unroll
    for (int e = 0; e < NEXP; e++) {
      lg[e] = acc[e] + tlog[b * NEXP + e];
      logits_out[(size_t)t * NEXP + e] = (float)lg[e];
    }
    int e0 = 0;
    for (int e = 1; e < NEXP; e++) if (lg[e] > lg[e0]) e0 = e;   // first idx wins ties
    int e1 = (e0 == 0) ? 1 : 0;
    for (int e = 0; e < NEXP; e++) if (e != e0 && lg[e] > lg[e1]) e1 = e;
    double p0 = 1.0 / (1.0 + exp(lg[e1] - lg[e0]));
    float g0f = (float)p0;
    float g1f = (float)(1.0 - p0);
    omega[t] = 1.0f - g0f;
    toke[t] = e0 | (e1 << 8);
    tg[t] = float2{g0f, g1f};
  }
}

// two-level routing: LDS ranks + 8 global atomics per block (256 total)
__global__ void k_route(const int* __restrict__ toke, const float2* __restrict__ tg,
                        int* __restrict__ counts, int* __restrict__ tokl,
                        float* __restrict__ gatel) {
  __shared__ int lcnt[NEXP];
  __shared__ int lbase[NEXP];
  const int tid = threadIdx.x;
  if (tid < NEXP) lcnt[tid] = 0;
  __syncthreads();
  const int t = blockIdx.x * 256 + tid;
  const int pe = toke[t];
  const int e0 = pe & 0xff, e1 = pe >> 8;
  const float2 g = tg[t];
  const int r0 = atomicAdd(&lcnt[e0], 1);
  const int r1 = atomicAdd(&lcnt[e1], 1);
  __syncthreads();
  if (tid < NEXP) lbase[tid] = atomicAdd(counts + tid, lcnt[tid]);
  __syncthreads();
  int i0 = lbase[e0] + r0;
  tokl[e0 * TOKENS + i0]  = (t << 1);
  gatel[e0 * TOKENS + i0] = g.x;
  int i1 = lbase[e1] + r1;
  tokl[e1 * TOKENS + i1]  = (t << 1) | 1;
  gatel[e1 * TOKENS + i1] = g.y;
}

// tiny: section offsets from counts
__global__ void k_soff(const int* __restrict__ cnts, int* __restrict__ soff, int* __restrict__ spc) {
  if (threadIdx.x == 0) {
    soff[8] = 0; spc[8] = TOKENS;
    int off = TOKENS;
    for (int e = 0; e < 8; e++) {
      int c = cnts[e];
      int p = (c + 127) & ~127;
      soff[e] = off; spc[e] = p;
      off += p;
    }
  }
}

// parallel row-metadata fill
__global__ void k_fill(const int* __restrict__ cnts, const int* __restrict__ soff,
                       const int* __restrict__ spc,
                       const int* __restrict__ tokl, const float* __restrict__ gatel,
                       const float* __restrict__ omega,
                       int* __restrict__ rmeta, float* __restrict__ rgate) {
  int r = blockIdx.x * 256 + threadIdx.x;
  if (r >= TROWS) return;
  if (r < TOKENS) { rmeta[r] = (r << 2) | 2; rgate[r] = omega[r]; return; }
  int meta = 3; float g = 0.f;
#pragma unroll
  for (int e = 0; e < 8; e++) {
    int off = soff[e];
    if (r >= off && r < off + spc[e]) {
      int i = r - off;
      if (i < cnts[e]) {
        int en = tokl[e * TOKENS + i];
        meta = ((en >> 1) << 2) | (en & 1);
        g = gatel[e * TOKENS + i];
      }
      break;
    }
  }
  rmeta[r] = meta; rgate[r] = g;
}

// gather X rows (f32 -> bf16) into k-slab layout xgp[s][row][32]
__global__ void k_gather(const float* __restrict__ x, const int* __restrict__ rmeta,
                         bf16_t* __restrict__ xgp) {
  int rbase = blockIdx.x * 128;
  for (int it = 0; it < 8; it++) {
    int id = it * 256 + threadIdx.x;
    int row = rbase + (id >> 4), s = id & 15;
    int meta = rmeta[row];
    union { bf16_t h[32]; uint4 u[4]; } t;
    if ((meta & 3) == 3) {
#pragma unroll
      for (int j = 0; j < 4; j++) t.u[j] = uint4{0, 0, 0, 0};
    } else {
      const float* src = x + (size_t)(meta >> 2) * D_MODEL + s * 32;
#pragma unroll
      for (int j = 0; j < 32; j += 4) {
        float4 v = *(const float4*)(src + j);
        t.h[j] = (bf16_t)v.x; t.h[j + 1] = (bf16_t)v.y;
        t.h[j + 2] = (bf16_t)v.z; t.h[j + 3] = (bf16_t)v.w;
      }
    }
    char* dst = (char*)xgp + ((size_t)s * TROWS + row) * 64;
#pragma unroll
    for (int j = 0; j < 4; j++) ((uint4*)dst)[j] = t.u[j];
  }
}

// GEMM1: h[rows][2048] = gelu(Xg @ W1 + b1); BK=32, 3-buffer depth-2 pipeline
__global__ __launch_bounds__(256) void k_gemm1(
    const bf16_t* __restrict__ xgp, const bf16_t* __restrict__ w1p,
    const bf16_t* __restrict__ uw1p,
    const float* __restrict__ b1, const float* __restrict__ ub1,
    const int* __restrict__ soff, const int* __restrict__ spc,
    bf16_t* __restrict__ hp) {
  const int sec = blockIdx.z, mt = blockIdx.x, ft = blockIdx.y;
  if (mt * 128 >= spc[sec]) return;
  const int groff = soff[sec];
  const char* Bbase = (const char*)((sec == 8) ? uw1p : (w1p + (size_t)sec * 16 * D_FF * 32));
  const float* bias = (sec == 8) ? ub1 : (b1 + sec * D_FF);

  // LDS: A buf[3][8192] @0, B buf[3][8192] @24576; epilogue overlay 128*136*2 = 34816
  __shared__ char smem[49152];
  const int tid = threadIdx.x, wave = tid >> 6, lane = tid & 63;
  const int l16 = lane & 15, quad = lane >> 4;
  const int wm = wave & 1, wn = wave >> 1;

  f32x4_t acc[4][4];
#pragma unroll
  for (int i = 0; i < 4; i++)
#pragma unroll
    for (int j = 0; j < 4; j++) acc[i][j] = f32x4_t{0.f, 0.f, 0.f, 0.f};

  // per-wave staging role: waves 0,1 -> A (4KB each), waves 2,3 -> B
  const char* gbase; size_t gstr; char* lbase;
  if (wave < 2) {
    gbase = (const char*)xgp + ((size_t)(groff + mt * 128)) * 64 + wave * 4096 + lane * 16;
    gstr  = (size_t)TROWS * 64;
    lbase = smem + wave * 4096;
  } else {
    gbase = Bbase + (size_t)ft * 128 * 64 + (wave - 2) * 4096 + lane * 16;
    gstr  = (size_t)D_FF * 64;
    lbase = smem + 24576 + (wave - 2) * 4096;
  }

  auto issue = [&](int s, int buf) {
    const char* g = gbase + (size_t)s * gstr;
    char* l = lbase + buf * 8192;
#pragma unroll
    for (int i = 0; i < 4; i++) load_lds16(g + i * 1024, l + i * 1024);
  };
  auto compute = [&](int buf) {
    const char* ab = smem + buf * 8192;
    const char* bb = smem + 24576 + buf * 8192;
    bf16x8_t af[4], bfr[4];
#pragma unroll
    for (int f = 0; f < 4; f++)
      af[f] = *(const bf16x8_t*)(ab + (wm * 64 + f * 16 + l16) * 64 + quad * 16);
#pragma unroll
    for (int f = 0; f < 4; f++)
      bfr[f] = *(const bf16x8_t*)(bb + (wn * 64 + f * 16 + l16) * 64 + quad * 16);
#pragma unroll
    for (int fm = 0; fm < 4; fm++)
#pragma unroll
      for (int fn = 0; fn < 4; fn++)
        acc[fm][fn] = mfma_bf16(af[fm], bfr[fn], acc[fm][fn]);
  };

  issue(0, 0);
  issue(1, 1);
  int bw = 2, br = 0;
  for (int s = 0; s < 14; s++) {
    issue(s + 2, bw);      // depth-2 prefetch
    if (++bw == 3) bw = 0;
    WAITCNT8;              // drain stage-s loads (oldest 4 of 12)
    RAWBAR;
    compute(br);
    if (++br == 3) br = 0;
    WAIT_LGKM0;            // ds_reads of reused buffer done before signaling
    RAWBAR;
  }
  WAITCNT4; RAWBAR; compute(br); if (++br == 3) br = 0; WAIT_LGKM0; RAWBAR;
  WAITCNT0; RAWBAR; compute(br);
  __syncthreads();         // all waves done with LDS tiles before epilogue overlay

  // epilogue: bias + fast gelu -> LDS [128][136] bf16 -> hp k-slab
  bf16_t* ep = (bf16_t*)smem;
#pragma unroll
  for (int fm = 0; fm < 4; fm++)
#pragma unroll
    for (int fn = 0; fn < 4; fn++)
#pragma unroll
      for (int i = 0; i < 4; i++) {
        int row = wm * 64 + fm * 16 + quad * 4 + i;
        int col = wn * 64 + fn * 16 + l16;
        float v = acc[fm][fn][i] + bias[ft * 128 + col];
        ep[row * 136 + col] = (bf16_t)fast_gelu(v);
      }
  __syncthreads();
#pragma unroll
  for (int i = 0; i < 2; i++) {
    int id = i * 256 + tid;
    int row = id & 127, cc = id >> 7;
    const uint4* src = (const uint4*)(ep + row * 136 + cc * 32);
    char* dst = (char*)hp + ((size_t)(ft * 4 + cc) * TROWS + groff + mt * 128 + row) * 64;
#pragma unroll
    for (int j = 0; j < 4; j++) ((uint4*)dst)[j] = src[j];
  }
}

// GEMM2: y[rows][512] = h @ W2 + b2, gate-scale, scatter; BK=32, 3-buffer depth-2
__global__ __launch_bounds__(256) void k_gemm2(
    const bf16_t* __restrict__ hp, const bf16_t* __restrict__ w2p,
    const bf16_t* __restrict__ uw2p,
    const float* __restrict__ b2, const float* __restrict__ ub2,
    const int* __restrict__ soff, const int* __restrict__ spc,
    const int* __restrict__ rmeta, const float* __restrict__ rgate,
    bf16_t* __restrict__ s0, bf16_t* __restrict__ s1, float* __restrict__ out) {
  const int sec = blockIdx.z, mt = blockIdx.x, nt = blockIdx.y;
  if (mt * 128 >= spc[sec]) return;
  const int groff = soff[sec];
  const char* Bbase = (const char*)((sec == 8) ? uw2p : (w2p + (size_t)sec * 64 * D_MODEL * 32));
  const float* bias = (sec == 8) ? ub2 : (b2 + sec * D_MODEL);

  __shared__ char smem[49152];
  const int tid = threadIdx.x, wave = tid >> 6, lane = tid & 63;
  const int l16 = lane & 15, quad = lane >> 4;
  const int wm = wave & 1, wn = wave >> 1;

  f32x4_t acc[4][4];
#pragma unroll
  for (int i = 0; i < 4; i++)
#pragma unroll
    for (int j = 0; j < 4; j++) acc[i][j] = f32x4_t{0.f, 0.f, 0.f, 0.f};

  const char* gbase; size_t gstr; char* lbase;
  if (wave < 2) {
    gbase = (const char*)hp + ((size_t)(groff + mt * 128)) * 64 + wave * 4096 + lane * 16;
    gstr  = (size_t)TROWS * 64;
    lbase = smem + wave * 4096;
  } else {
    gbase = Bbase + (size_t)nt * 128 * 64 + (wave - 2) * 4096 + lane * 16;
    gstr  = (size_t)D_MODEL * 64;
    lbase = smem + 24576 + (wave - 2) * 4096;
  }

  auto issue = [&](int s, int buf) {
    const char* g = gbase + (size_t)s * gstr;
    char* l = lbase + buf * 8192;
#pragma unroll
    for (int i = 0; i < 4; i++) load_lds16(g + i * 1024, l + i * 1024);
  };
  auto compute = [&](int buf) {
    const char* ab = smem + buf * 8192;
    const char* bb = smem + 24576 + buf * 8192;
    bf16x8_t af[4], bfr[4];
#pragma unroll
    for (int f = 0; f < 4; f++)
      af[f] = *(const bf16x8_t*)(ab + (wm * 64 + f * 16 + l16) * 64 + quad * 16);
#pragma unroll
    for (int f = 0; f < 4; f++)
      bfr[f] = *(const bf16x8_t*)(bb + (wn * 64 + f * 16 + l16) * 64 + quad * 16);
#pragma unroll
    for (int fm = 0; fm < 4; fm++)
#pragma unroll
      for (int fn = 0; fn < 4; fn++)
        acc[fm][fn] = mfma_bf16(af[fm], bfr[fn], acc[fm][fn]);
  };

  issue(0, 0);
  issue(1, 1);
  int bw = 2, br = 0;
  for (int s = 0; s < 62; s++) {
    issue(s + 2, bw);
    if (++bw == 3) bw = 0;
    WAITCNT8;
    RAWBAR;
    compute(br);
    if (++br == 3) br = 0;
    WAIT_LGKM0;
    RAWBAR;
  }
  WAITCNT4; RAWBAR; compute(br); if (++br == 3) br = 0; WAIT_LGKM0; RAWBAR;
  WAITCNT0; RAWBAR; compute(br);

  // epilogue: +b2, *gate, scatter by slot (registers + global only)
#pragma unroll
  for (int fm = 0; fm < 4; fm++) {
#pragma unroll
    for (int i = 0; i < 4; i++) {
      int grow = groff + mt * 128 + wm * 64 + fm * 16 + quad * 4 + i;
      int meta = rmeta[grow];
      int slot = meta & 3;
      if (slot == 3) continue;
      float g = rgate[grow];
      size_t tkoff = (size_t)(meta >> 2) * D_MODEL;
      if (slot == 2) {
        float* dst = out + tkoff;
#pragma unroll
        for (int fn = 0; fn < 4; fn++) {
          int d = nt * 128 + wn * 64 + fn * 16 + l16;
          dst[d] = (acc[fm][fn][i] + bias[d]) * g;
        }
      } else {
        bf16_t* dst = (slot ? s1 : s0) + tkoff;
#pragma unroll
        for (int fn = 0; fn < 4; fn++) {
          int d = nt * 128 + wn * 64 + fn * 16 + l16;
          dst[d] = (bf16_t)((acc[fm][fn][i] + bias[d]) * g);
        }
      }
    }
  }
}

__global__ void k_combine(const bf16x4_t* __restrict__ s0, const bf16x4_t* __restrict__ s1,
                          float4* __restrict__ out, int n4) {
  int i = blockIdx.x * blockDim.x + threadIdx.x;
  if (i >= n4) return;
  bf16x4_t a = s0[i], b = s1[i];
  float4 o = out[i];
  o.x += (float)a[0] + (float)b[0];
  o.y += (float)a[1] + (float)b[1];
  o.z += (float)a[2] + (float)b[2];
  o.w += (float)a[3] + (float)b[3];
  out[i] = o;
}

extern "C" void kernel_launch(void* const* d_in, const int* in_sizes, int n_in,
                              void* d_out, int out_size, void* d_ws, size_t ws_size,
                              hipStream_t stream) {
  (void)in_sizes; (void)n_in; (void)out_size; (void)ws_size;
  const float* x        = (const float*)d_in[0];
  const int*   task_ids = (const int*)  d_in[1];
  const float* task_emb = (const float*)d_in[2];
  const float* gate_w   = (const float*)d_in[3];
  const float* gate_b   = (const float*)d_in[4];
  const float* w1       = (const float*)d_in[5];
  const float* b1       = (const float*)d_in[6];
  const float* w2       = (const float*)d_in[7];
  const float* b2       = (const float*)d_in[8];
  const float* uw1      = (const float*)d_in[9];
  const float* ub1      = (const float*)d_in[10];
  const float* uw2      = (const float*)d_in[11];
  const float* ub2      = (const float*)d_in[12];

  char* ws = (char*)d_ws;
  bf16_t* w1p   = (bf16_t*)(ws + W1P_OFF);
  bf16_t* uw1p  = (bf16_t*)(ws + UW1P_OFF);
  bf16_t* w2p   = (bf16_t*)(ws + W2P_OFF);
  bf16_t* uw2p  = (bf16_t*)(ws + UW2P_OFF);
  bf16_t* s0    = (bf16_t*)(ws + S0_OFF);
  bf16_t* s1    = (bf16_t*)(ws + S1_OFF);
  int*    cnts  = (int*)   (ws + CNT_OFF);
  int*    tokl  = (int*)   (ws + TOKL_OFF);
  float*  gatel = (float*) (ws + GATEL_OFF);
  float*  omg   = (float*) (ws + OMEGA_OFF);
  double* tlog  = (double*)(ws + TLOG_OFF);
  int*    soff  = (int*)   (ws + SOFF_OFF);
  int*    spc   = (int*)   (ws + SPC_OFF);
  int*    rmeta = (int*)   (ws + RMETA_OFF);
  float*  rgate = (float*) (ws + RGATE_OFF);
  bf16_t* xgp   = (bf16_t*)(ws + XGP_OFF);
  bf16_t* hp    = (bf16_t*)(ws + HP_OFF);
  int*    toke  = (int*)   (ws + TOKE_OFF);
  float2* tg    = (float2*)(ws + TG_OFF);

  float* out    = (float*)d_out;
  float* logits = out + (size_t)TOKENS * D_MODEL;

  hipMemsetAsync(cnts, 0, 64, stream);

  k_pack<<<dim3(32, 8, NEXP), 256, 0, stream>>>(w1, w1p, D_MODEL, D_FF);
  k_pack<<<dim3(8, 32, NEXP), 256, 0, stream>>>(w2, w2p, D_FF, D_MODEL);
  k_pack<<<dim3(32, 8, 1),    256, 0, stream>>>(uw1, uw1p, D_MODEL, D_FF);
  k_pack<<<dim3(8, 32, 1),    256, 0, stream>>>(uw2, uw2p, D_FF, D_MODEL);
  k_tlog<<<1, 64, 0, stream>>>(task_ids, task_emb, gate_w, gate_b, tlog);
  k_gate<<<dim3(TOKENS / 4), 256, 0, stream>>>(x, gate_w, tlog, logits, toke, tg, omg);
  k_route<<<dim3(TOKENS / 256), 256, 0, stream>>>(toke, tg, cnts, tokl, gatel);
  k_soff<<<1, 64, 0, stream>>>(cnts, soff, spc);
  k_fill<<<dim3((TROWS + 255) / 256), 256, 0, stream>>>(cnts, soff, spc, tokl, gatel, omg,
                                                        rmeta, rgate);
  k_gather<<<dim3(TROWS / 128), 256, 0, stream>>>(x, rmeta, xgp);
  k_gemm1<<<dim3(64, 16, 9), 256, 0, stream>>>(xgp, w1p, uw1p, b1, ub1, soff, spc, hp);
  k_gemm2<<<dim3(64, 4, 9), 256, 0, stream>>>(hp, w2p, uw2p, b2, ub2, soff, spc,
                                              rmeta, rgate, s0, s1, out);
  const int n4 = TOKENS * D_MODEL / 4;
  k_combine<<<dim3(n4 / 256), 256, 0, stream>>>((const bf16x4_t*)s0, (const bf16x4_t*)s1,
                                                (float4*)out, n4);
}